// Round 7
// baseline (133.089 us; speedup 1.0000x reference)
//
#include <hip/hip_runtime.h>
#include <math.h>

#define BSZ 4096
#define DIM 128
#define K_TOP 200
#define TGUESS 0.11f
#define HBINS 512         // linear bins over [0.1, 0.74), width 0.00125
#define ROWS 8            // anchor rows per block (R19: was 16)

typedef unsigned short u16;
typedef unsigned int u32;
typedef __attribute__((ext_vector_type(8))) short bf16x8;
typedef __attribute__((ext_vector_type(4))) float floatx4;

__device__ inline u16 f2bf(float x) {  // fp32 -> bf16 RNE
    u32 u = __float_as_uint(x);
    return (u16)((u + 0x7fffu + ((u >> 16) & 1u)) >> 16);
}

// ---------------- pre: F -> bf16 ----------------
__global__ __launch_bounds__(256) void pre_kernel(const float* __restrict__ F,
                                                  u16* __restrict__ Fb) {
    int idx = blockIdx.x * 256 + threadIdx.x;
    if (idx < BSZ * DIM / 4) {
        float4 v = ((const float4*)F)[idx];
        ushort4 r;
        r.x = f2bf(v.x); r.y = f2bf(v.y); r.z = f2bf(v.z); r.w = f2bf(v.w);
        ((ushort4*)Fb)[idx] = r;
    }
}

// ---------------- fused kernel: GEMM + histogram-of-exp + top-k + loss ----------------
// R19: TLP instead of ILP. Five rounds (R13-R18) proved the compiler caps
// VGPR at 64 (LDS prices 2 blocks/CU) and kills/spills any register double
// buffer. So stop fighting: supply the 2nd resident block. Grid = 512 blocks
// of 8 rows each -> 2 blocks/CU = 32 waves/CU = 8 waves/SIMD, double the
// latency hiding, using the 64-VGPR code the compiler naturally emits.
//  - A rows duplicated (l16&7): MFMA output rows 8-15 replicate 0-7. The
//    epilogue splits by column-half instead: quads 0-1 process a0 (cols
//    +0..15), quads 2-3 process a1 (cols +16..31) -> every lane handles 4
//    valid elements, no idle lanes, per-CU epilogue work unchanged.
//  - LDS halves to ~37 KB (8-row histograms) so 2 blocks fit (74<160 KB).
//  - positive fold gains shfl_xor(.,32) to merge quad pairs (0<->2, 1<->3).
//  - keeps R17's measured-best branchy epilogue + plain in-loop loads.
__global__ __launch_bounds__(1024, 8) void fused_all(const u16* __restrict__ Fb,
                                                     const int* __restrict__ labels,
                                                     float2* __restrict__ rowout) {
    __shared__ int   hcnt[ROWS * HBINS];       // 16 KB  [row][bin]
    __shared__ float hexp[ROWS * HBINS];       // 16 KB  [row][bin]
    __shared__ unsigned char labc[BSZ];        // 4 KB
    __shared__ float ps[ROWS], pe[ROWS], pc[ROWS];

    const int tid  = threadIdx.x;
    const int wave = tid >> 6, lane = tid & 63;
    const int l16  = lane & 15, quad = lane >> 4;
    const int hi   = quad >> 1;                // column half: 0 -> a0, 1 -> a1
    const int q1   = quad & 1;                 // row group: rows q1*4 .. q1*4+3
    const int brow = blockIdx.x * ROWS;

    // ---- init ----
    {
        int4 lv = ((const int4*)labels)[tid];          // BSZ/4 == 1024 == blockDim
        uchar4 r;
        r.x = (unsigned char)lv.x; r.y = (unsigned char)lv.y;
        r.z = (unsigned char)lv.z; r.w = (unsigned char)lv.w;
        ((uchar4*)labc)[tid] = r;
    }
    #pragma unroll
    for (int q = 0; q < 4; ++q) { hcnt[q * 1024 + tid] = 0; hexp[q * 1024 + tid] = 0.f; }
    if (tid < ROWS) { ps[tid] = 0.f; pe[tid] = 0.f; pc[tid] = 0.f; }
    __syncthreads();

    // ---- A fragments: rows duplicated so MFMA rows 8-15 == rows 0-7 ----
    const u16* Ab = Fb + (size_t)(brow + (l16 & 7)) * DIM + quad * 8;
    bf16x8 afr[4];
    #pragma unroll
    for (int ks = 0; ks < 4; ++ks) afr[ks] = *(const bf16x8*)(Ab + ks * 32);

    unsigned char labr_[4];
    #pragma unroll
    for (int e = 0; e < 4; ++e) labr_[e] = labc[brow + q1 * 4 + e];

    // column labels for this lane's 8 sub-tiles -> registers (static index)
    unsigned char lcol[8];
    #pragma unroll
    for (int i = 0; i < 8; ++i) lcol[i] = labc[wave * 256 + i * 32 + hi * 16 + l16];

    // register accumulators for positives (rows q1*4+e)
    float pps[4] = {0.f, 0.f, 0.f, 0.f};
    float ppe[4] = {0.f, 0.f, 0.f, 0.f};
    float ppc[4] = {0.f, 0.f, 0.f, 0.f};

    // ---- phase 1: sweep 8 n-tiles of 32 cols (compiler-scheduled loads) ----
    const u16* Bw = Fb + (size_t)(wave * 256 + l16) * DIM + quad * 8;
    #pragma unroll
    for (int t = 0; t < 8; ++t) {
        const u16* B0 = Bw + (size_t)t * 32 * DIM;
        const u16* B1 = B0 + 16 * DIM;
        floatx4 a0 = (floatx4){0.f, 0.f, 0.f, 0.f};
        floatx4 a1 = (floatx4){0.f, 0.f, 0.f, 0.f};
        #pragma unroll
        for (int ks = 0; ks < 4; ++ks) {
            bf16x8 b0 = *(const bf16x8*)(B0 + ks * 32);
            bf16x8 b1 = *(const bf16x8*)(B1 + ks * 32);
            a0 = __builtin_amdgcn_mfma_f32_16x16x32_bf16(afr[ks], b0, a0, 0, 0, 0);
            a1 = __builtin_amdgcn_mfma_f32_16x16x32_bf16(afr[ks], b1, a1, 0, 0, 0);
        }
        // epilogue: col = tn0 + hi*16 + l16, row = q1*4+e (dup'd C rows) [m89/m91]
        const int tn0 = wave * 256 + t * 32;
        const floatx4 accv = hi ? a1 : a0;
        const int cg_ = tn0 + hi * 16 + l16;           // global col (this lane's half)
        const int lc = lcol[t];                        // register, static index
        #pragma unroll
        for (int e = 0; e < 4; ++e) {
            const int rl = q1 * 4 + e;
            const int rg = brow + rl;
            if (cg_ == rg) continue;                   // diagonal
            const float s = accv[e];
            const bool pos = (lc == (int)labr_[e]);    // positive (~41/row total)
            if (pos | (s > TGUESS)) {
                const float ex = __expf((s - 1.f) * 10.f);
                if (pos) {                             // register accumulate
                    pps[e] += s; ppe[e] += ex; ppc[e] += 1.f;
                } else {                               // hard negative -> histogram
                    int b = (int)((s - 0.1f) * 800.f);
                    b = b < 0 ? 0 : (b > HBINS - 1 ? HBINS - 1 : b);
                    atomicAdd(&hcnt[rl * HBINS + b], 1);     // fire-and-forget
                    atomicAdd(&hexp[rl * HBINS + b], ex);    // fire-and-forget
                }
            }
        }
    }

    // ---- fold positive partials: l16 group then quad-pair (xor 32), 1 atomic/row ----
    #pragma unroll
    for (int e = 0; e < 4; ++e) {
        float a = pps[e], b = ppe[e], c = ppc[e];
        #pragma unroll
        for (int off = 8; off; off >>= 1) {
            a += __shfl_xor(a, off);
            b += __shfl_xor(b, off);
            c += __shfl_xor(c, off);
        }
        a += __shfl_xor(a, 32);                        // quad 0<->2, 1<->3 (same rows)
        b += __shfl_xor(b, 32);
        c += __shfl_xor(c, 32);
        if (l16 == 0 && quad < 2) {
            const int rl = q1 * 4 + e;
            atomicAdd(&ps[rl], a);
            atomicAdd(&pe[rl], b);
            atomicAdd(&pc[rl], c);
        }
    }
    __syncthreads();

    // ---- phase 2: wave r (r<8) = threshold bin + loss for row r ----
    if (wave < ROWS) {
        const int r = wave;
        const int* hc = hcnt + r * HBINS;
        const float* hx = hexp + r * HBINS;

        int local[8], csum = 0;                        // lane owns bins [lane*8, lane*8+8)
        #pragma unroll
        for (int t2 = 0; t2 < 8; ++t2) { local[t2] = hc[lane * 8 + t2]; csum += local[t2]; }
        int suf = csum;
        #pragma unroll
        for (int off = 1; off < 64; off <<= 1) {       // wave suffix-sum
            int t2 = __shfl_down(suf, off);
            if (lane + off < 64) suf += t2;
        }
        const int above = suf - csum;
        const bool owner = (above < K_TOP) && (suf >= K_TOP);
        int b1o = 0, c1o = 0;
        if (owner) {
            int acc2 = above;
            #pragma unroll
            for (int t2 = 7; t2 >= 0; --t2) {
                if (acc2 + local[t2] >= K_TOP) { b1o = lane * 8 + t2; c1o = acc2; break; }
                acc2 += local[t2];
            }
        }
        unsigned long long bm = __ballot(owner);
        int b1, K2;
        if (bm == 0ull) {            // fewer than K_TOP candidates: take them all
            b1 = -1; K2 = 0;
        } else {
            const int src = __ffsll((long long)bm) - 1;
            b1 = __shfl(b1o, src);
            K2 = K_TOP - __shfl(c1o, src);
        }

        float te = 0.f;                                // exact exp-sum above bin b1
        #pragma unroll
        for (int t2 = 0; t2 < 8; ++t2) {
            const int b = lane * 8 + t2;
            if (b > b1) te += hx[b];
        }
        #pragma unroll
        for (int off = 32; off; off >>= 1) te += __shfl_down(te, off);

        if (lane == 0) {
            float tsum = 0.f;
            if (K2 > 0) {
                const int cb = hc[b1];
                if (cb > 0) tsum = (float)K2 * hx[b1] / (float)cb;  // in-bin average
            }
            const float pcnt = pc[r];
            const int labi = labc[brow + r];
            float pr = 0.f, vd = 0.f;
            if (labi > 0 && pcnt > 0.f) {
                float denom = pe[r] + te + tsum;
                float slp = 10.f * (ps[r] - pcnt) - pcnt * logf(denom);
                pr = -2.f * slp / pcnt;
                vd = 1.f;
            }
            rowout[brow + r] = make_float2(pr, vd);
        }
    }
}

// ---------------- tree-reduce 4096 row results -> scalar ----------------
__global__ __launch_bounds__(256) void reduce_kernel(const float2* __restrict__ rowout,
                                                     float* __restrict__ out) {
    __shared__ float reda[4], redb[4];
    const int tid = threadIdx.x, lane = tid & 63, w = tid >> 6;
    float sa = 0.f, sb = 0.f;
    #pragma unroll
    for (int j = 0; j < 16; ++j) {
        float2 v = rowout[j * 256 + tid];
        sa += v.x; sb += v.y;
    }
    #pragma unroll
    for (int off = 32; off; off >>= 1) {
        sa += __shfl_down(sa, off);
        sb += __shfl_down(sb, off);
    }
    if (lane == 0) { reda[w] = sa; redb[w] = sb; }
    __syncthreads();
    if (tid == 0)
        out[0] = (reda[0] + reda[1] + reda[2] + reda[3]) /
                 (redb[0] + redb[1] + redb[2] + redb[3]);
}

extern "C" void kernel_launch(void* const* d_in, const int* in_sizes, int n_in,
                              void* d_out, int out_size, void* d_ws, size_t ws_size,
                              hipStream_t stream) {
    const float* F      = (const float*)d_in[0];
    const int*   labels = (const int*)d_in[1];
    float*       out    = (float*)d_out;

    char* w = (char*)d_ws;
    u16*    Fb     = (u16*)w;               w += (size_t)BSZ * DIM * 2;   // 1 MB
    float2* rowout = (float2*)w;            w += (size_t)BSZ * 8;         // 32 KB

    pre_kernel<<<512, 256, 0, stream>>>(F, Fb);
    fused_all<<<512, 1024, 0, stream>>>(Fb, labels, rowout);
    reduce_kernel<<<1, 256, 0, stream>>>(rowout, out);
}

// Round 8
// 112.186 us; speedup vs baseline: 1.1863x; 1.1863x over previous
//
#include <hip/hip_runtime.h>
#include <math.h>

#define BSZ 4096
#define DIM 128
#define K_TOP 200
#define TGUESS 0.11f
#define HBINS 512         // linear bins over [0.1, 0.74), width 0.00125

typedef unsigned short u16;
typedef unsigned int u32;
typedef __attribute__((ext_vector_type(8))) short bf16x8;
typedef __attribute__((ext_vector_type(4))) float floatx4;

__device__ inline u16 f2bf(float x) {  // fp32 -> bf16 RNE
    u32 u = __float_as_uint(x);
    return (u16)((u + 0x7fffu + ((u >> 16) & 1u)) >> 16);
}

// ---------------- pre: F -> bf16 ----------------
__global__ __launch_bounds__(256) void pre_kernel(const float* __restrict__ F,
                                                  u16* __restrict__ Fb) {
    int idx = blockIdx.x * 256 + threadIdx.x;
    if (idx < BSZ * DIM / 4) {
        float4 v = ((const float4*)F)[idx];
        ushort4 r;
        r.x = f2bf(v.x); r.y = f2bf(v.y); r.z = f2bf(v.z); r.w = f2bf(v.w);
        ((ushort4*)Fb)[idx] = r;
    }
}

// ---------------- fused kernel: GEMM + histogram-of-exp + top-k + loss ----------------
// Grid = 256 blocks (one/CU), 1024 threads = 16 waves. Block owns 16 anchor
// rows x all 4096 cols; wave w sweeps cols [w*256, w*256+256).
// R20 = R17 structure (measured ~39us floor) + ONLY the flat epilogue:
//  - R19 disproved latency-exposure: 2 blocks/CU (80% occupancy) scaled time
//    exactly with per-CU instruction work (39 -> 78.5us, zero overlap gain).
//    The limiter tracks the issued instruction stream, not VALU/MFMA/DS/HBM
//    (all <30% busy). Remaining unmeasured consumer: SALU/exec-mask branch
//    cascades in the epilogue -- 2 divergent branches per element-iter,
//    ~always entered at wave level (P(any lane hot) ~ 99.9%).
//  - flat epilogue: ndiag/pos as mask bits (no `continue`), unconditional
//    __expf, cndmask positive accumulate, ONE exec-masked region for the
//    2 histogram atomics. (R18 had this but its measurement was destroyed
//    by register-dbuf scratch spills; measured clean here.)
__global__ __launch_bounds__(1024, 4) void fused_all(const u16* __restrict__ Fb,
                                                     const int* __restrict__ labels,
                                                     float2* __restrict__ rowout) {
    __shared__ int   hcnt[16 * HBINS];         // 32 KB  [row][bin]
    __shared__ float hexp[16 * HBINS];         // 32 KB  [row][bin]
    __shared__ unsigned char labc[BSZ];        // 4 KB
    __shared__ float ps[16], pe[16], pc[16];

    const int tid  = threadIdx.x;
    const int wave = tid >> 6, lane = tid & 63;
    const int l16  = lane & 15, quad = lane >> 4;
    const int brow = blockIdx.x * 16;

    // ---- init ----
    {
        int4 lv = ((const int4*)labels)[tid];          // BSZ/4 == 1024 == blockDim
        uchar4 r;
        r.x = (unsigned char)lv.x; r.y = (unsigned char)lv.y;
        r.z = (unsigned char)lv.z; r.w = (unsigned char)lv.w;
        ((uchar4*)labc)[tid] = r;
    }
    #pragma unroll
    for (int q = 0; q < 8; ++q) { hcnt[q * 1024 + tid] = 0; hexp[q * 1024 + tid] = 0.f; }
    if (tid < 16) { ps[tid] = 0.f; pe[tid] = 0.f; pc[tid] = 0.f; }
    __syncthreads();

    // ---- A fragments in registers for the whole sweep ----
    const u16* Ab = Fb + (size_t)(brow + l16) * DIM + quad * 8;
    bf16x8 afr[4];
    #pragma unroll
    for (int ks = 0; ks < 4; ++ks) afr[ks] = *(const bf16x8*)(Ab + ks * 32);

    unsigned char labr_[4];
    #pragma unroll
    for (int e = 0; e < 4; ++e) labr_[e] = labc[brow + quad * 4 + e];

    // column labels for this wave's 16 sub-tiles -> registers (static index)
    unsigned char lcol[16];
    #pragma unroll
    for (int i = 0; i < 16; ++i) lcol[i] = labc[wave * 256 + i * 16 + l16];

    // register accumulators for positives (rows quad*4+e)
    float pps[4] = {0.f, 0.f, 0.f, 0.f};
    float ppe[4] = {0.f, 0.f, 0.f, 0.f};
    float ppc[4] = {0.f, 0.f, 0.f, 0.f};

    // ---- phase 1: sweep 8 n-tiles of 32 cols (compiler-scheduled loads) ----
    const u16* Bw = Fb + (size_t)(wave * 256 + l16) * DIM + quad * 8;
    #pragma unroll
    for (int t = 0; t < 8; ++t) {
        const u16* B0 = Bw + (size_t)t * 32 * DIM;
        const u16* B1 = B0 + 16 * DIM;
        floatx4 a0 = (floatx4){0.f, 0.f, 0.f, 0.f};
        floatx4 a1 = (floatx4){0.f, 0.f, 0.f, 0.f};
        #pragma unroll
        for (int ks = 0; ks < 4; ++ks) {
            bf16x8 b0 = *(const bf16x8*)(B0 + ks * 32);
            bf16x8 b1 = *(const bf16x8*)(B1 + ks * 32);
            a0 = __builtin_amdgcn_mfma_f32_16x16x32_bf16(afr[ks], b0, a0, 0, 0, 0);
            a1 = __builtin_amdgcn_mfma_f32_16x16x32_bf16(afr[ks], b1, a1, 0, 0, 0);
        }
        // flat epilogue: col = l16 (B side), row = quad*4+e (A side) [m89/m91]
        const int tn0 = wave * 256 + t * 32;
        #pragma unroll
        for (int nt = 0; nt < 2; ++nt) {
            const floatx4 accv = nt ? a1 : a0;
            const int cg_ = tn0 + nt * 16 + l16;       // global col
            const int lc = lcol[t * 2 + nt];           // register, static index
            #pragma unroll
            for (int e = 0; e < 4; ++e) {
                const int rl = quad * 4 + e;
                const int rg = brow + rl;
                const float s = accv[e];
                const bool ndiag = (cg_ != rg);
                const bool pos = (lc == (int)labr_[e]) & ndiag;
                const float ex = __expf((s - 1.f) * 10.f);   // unconditional
                pps[e] += pos ? s : 0.f;                     // cndmask accumulate
                ppe[e] += pos ? ex : 0.f;
                ppc[e] += pos ? 1.f : 0.f;
                int b = (int)((s - 0.1f) * 800.f);
                b = b < 0 ? 0 : (b > HBINS - 1 ? HBINS - 1 : b);
                if (ndiag & !pos & (s > TGUESS)) {           // single masked region
                    atomicAdd(&hcnt[rl * HBINS + b], 1);     // fire-and-forget
                    atomicAdd(&hexp[rl * HBINS + b], ex);    // fire-and-forget
                }
            }
        }
    }

    // ---- fold positive partials: reduce over the 16-lane l16 group, 1 atomic/row/wave ----
    #pragma unroll
    for (int e = 0; e < 4; ++e) {
        float a = pps[e], b = ppe[e], c = ppc[e];
        #pragma unroll
        for (int off = 8; off; off >>= 1) {
            a += __shfl_xor(a, off);
            b += __shfl_xor(b, off);
            c += __shfl_xor(c, off);
        }
        if (l16 == 0) {
            const int rl = quad * 4 + e;
            atomicAdd(&ps[rl], a);
            atomicAdd(&pe[rl], b);
            atomicAdd(&pc[rl], c);
        }
    }
    __syncthreads();

    // ---- phase 2: wave r = threshold bin + loss for row r (wave-private) ----
    {
        const int r = wave;
        const int* hc = hcnt + r * HBINS;
        const float* hx = hexp + r * HBINS;

        int local[8], csum = 0;                        // lane owns bins [lane*8, lane*8+8)
        #pragma unroll
        for (int t2 = 0; t2 < 8; ++t2) { local[t2] = hc[lane * 8 + t2]; csum += local[t2]; }
        int suf = csum;
        #pragma unroll
        for (int off = 1; off < 64; off <<= 1) {       // wave suffix-sum
            int t2 = __shfl_down(suf, off);
            if (lane + off < 64) suf += t2;
        }
        const int above = suf - csum;
        const bool owner = (above < K_TOP) && (suf >= K_TOP);
        int b1o = 0, c1o = 0;
        if (owner) {
            int acc2 = above;
            #pragma unroll
            for (int t2 = 7; t2 >= 0; --t2) {
                if (acc2 + local[t2] >= K_TOP) { b1o = lane * 8 + t2; c1o = acc2; break; }
                acc2 += local[t2];
            }
        }
        unsigned long long bm = __ballot(owner);
        int b1, K2;
        if (bm == 0ull) {            // fewer than K_TOP candidates: take them all
            b1 = -1; K2 = 0;
        } else {
            const int src = __ffsll((long long)bm) - 1;
            b1 = __shfl(b1o, src);
            K2 = K_TOP - __shfl(c1o, src);
        }

        float te = 0.f;                                // exact exp-sum above bin b1
        #pragma unroll
        for (int t2 = 0; t2 < 8; ++t2) {
            const int b = lane * 8 + t2;
            if (b > b1) te += hx[b];
        }
        #pragma unroll
        for (int off = 32; off; off >>= 1) te += __shfl_down(te, off);

        if (lane == 0) {
            float tsum = 0.f;
            if (K2 > 0) {
                const int cb = hc[b1];
                if (cb > 0) tsum = (float)K2 * hx[b1] / (float)cb;  // in-bin average
            }
            const float pcnt = pc[r];
            const int labi = labc[brow + r];
            float pr = 0.f, vd = 0.f;
            if (labi > 0 && pcnt > 0.f) {
                float denom = pe[r] + te + tsum;
                float slp = 10.f * (ps[r] - pcnt) - pcnt * logf(denom);
                pr = -2.f * slp / pcnt;
                vd = 1.f;
            }
            rowout[brow + r] = make_float2(pr, vd);
        }
    }
}

// ---------------- tree-reduce 4096 row results -> scalar ----------------
__global__ __launch_bounds__(256) void reduce_kernel(const float2* __restrict__ rowout,
                                                     float* __restrict__ out) {
    __shared__ float reda[4], redb[4];
    const int tid = threadIdx.x, lane = tid & 63, w = tid >> 6;
    float sa = 0.f, sb = 0.f;
    #pragma unroll
    for (int j = 0; j < 16; ++j) {
        float2 v = rowout[j * 256 + tid];
        sa += v.x; sb += v.y;
    }
    #pragma unroll
    for (int off = 32; off; off >>= 1) {
        sa += __shfl_down(sa, off);
        sb += __shfl_down(sb, off);
    }
    if (lane == 0) { reda[w] = sa; redb[w] = sb; }
    __syncthreads();
    if (tid == 0)
        out[0] = (reda[0] + reda[1] + reda[2] + reda[3]) /
                 (redb[0] + redb[1] + redb[2] + redb[3]);
}

extern "C" void kernel_launch(void* const* d_in, const int* in_sizes, int n_in,
                              void* d_out, int out_size, void* d_ws, size_t ws_size,
                              hipStream_t stream) {
    const float* F      = (const float*)d_in[0];
    const int*   labels = (const int*)d_in[1];
    float*       out    = (float*)d_out;

    char* w = (char*)d_ws;
    u16*    Fb     = (u16*)w;               w += (size_t)BSZ * DIM * 2;   // 1 MB
    float2* rowout = (float2*)w;            w += (size_t)BSZ * 8;         // 32 KB

    pre_kernel<<<512, 256, 0, stream>>>(F, Fb);
    fused_all<<<256, 1024, 0, stream>>>(Fb, labels, rowout);
    reduce_kernel<<<1, 256, 0, stream>>>(rowout, out);
}

// Round 9
// 81.793 us; speedup vs baseline: 1.6271x; 1.3716x over previous
//
#include <hip/hip_runtime.h>
#include <math.h>

#define BSZ 4096
#define DIM 128
#define K_TOP 200
#define TGUESS 0.11f
#define HBINS 512         // linear bins over [0.1, 0.74), width 0.00125

typedef unsigned short u16;
typedef unsigned int u32;
typedef __attribute__((ext_vector_type(8))) short bf16x8;
typedef __attribute__((ext_vector_type(4))) float floatx4;

__device__ inline u16 f2bf(float x) {  // fp32 -> bf16 RNE
    u32 u = __float_as_uint(x);
    return (u16)((u + 0x7fffu + ((u >> 16) & 1u)) >> 16);
}

// ---------------- pre: F -> bf16, packed in MFMA-fragment order ----------------
// R21 layout: element (row r, dim d) lives at
//   chunk = (r>>4)*4 + (d>>5)        [1 KB chunks: 16 rows x 32 dims]
//   slot  = ((d>>3)&3)*16 + (r&15)   [16 B per lane-slot]
// so a fragment load in fused_all is base + chunk*1024 + lane*16:
// 64 lanes read 1 KB CONTIGUOUS -> 16 cache lines/load (minimum), vs 32
// lines (2 lanes/line) in the row-major layout. R19 proved time tracks the
// per-CU VMEM stream (epilogue-constant, loads-doubled -> time doubled);
// this halves the L1/TA line-request work per byte at identical bytes,
// instruction count, and per-lane MFMA operand values.
__global__ __launch_bounds__(256) void pre_kernel(const float* __restrict__ F,
                                                  u16* __restrict__ Fb) {
    const int u = blockIdx.x * 256 + threadIdx.x;  // [0, 65536)
    const int r = u >> 4;                          // row 0..4095
    const int g = u & 15;                          // 8-dim group 0..15
    const float4 v0 = ((const float4*)(F + r * DIM + g * 8))[0];
    const float4 v1 = ((const float4*)(F + r * DIM + g * 8))[1];
    u32 p0 = (u32)f2bf(v0.x) | ((u32)f2bf(v0.y) << 16);
    u32 p1 = (u32)f2bf(v0.z) | ((u32)f2bf(v0.w) << 16);
    u32 p2 = (u32)f2bf(v1.x) | ((u32)f2bf(v1.y) << 16);
    u32 p3 = (u32)f2bf(v1.z) | ((u32)f2bf(v1.w) << 16);
    const int chunk = (r >> 4) * 4 + (g >> 2);
    const int slot  = (g & 3) * 16 + (r & 15);
    ((int4*)Fb)[chunk * 64 + slot] = make_int4((int)p0, (int)p1, (int)p2, (int)p3);
}

// ---------------- fused kernel: GEMM + histogram-of-exp + top-k + loss ----------------
// Grid = 256 blocks (one/CU), 1024 threads = 16 waves. Block owns 16 anchor
// rows x all 4096 cols; wave w sweeps cols [w*256, w*256+256).
// R21 = R17 structure (measured ~39us floor; branchy epilogue -- R20 proved
// the flat one spills at the 64-VGPR cap) + packed-layout fragment loads.
__global__ __launch_bounds__(1024, 4) void fused_all(const u16* __restrict__ Fb,
                                                     const int* __restrict__ labels,
                                                     float2* __restrict__ rowout) {
    __shared__ int   hcnt[16 * HBINS];         // 32 KB  [row][bin]
    __shared__ float hexp[16 * HBINS];         // 32 KB  [row][bin]
    __shared__ unsigned char labc[BSZ];        // 4 KB
    __shared__ float ps[16], pe[16], pc[16];

    const int tid  = threadIdx.x;
    const int wave = tid >> 6, lane = tid & 63;
    const int l16  = lane & 15, quad = lane >> 4;
    const int brow = blockIdx.x * 16;

    // ---- init ----
    {
        int4 lv = ((const int4*)labels)[tid];          // BSZ/4 == 1024 == blockDim
        uchar4 r;
        r.x = (unsigned char)lv.x; r.y = (unsigned char)lv.y;
        r.z = (unsigned char)lv.z; r.w = (unsigned char)lv.w;
        ((uchar4*)labc)[tid] = r;
    }
    #pragma unroll
    for (int q = 0; q < 8; ++q) { hcnt[q * 1024 + tid] = 0; hexp[q * 1024 + tid] = 0.f; }
    if (tid < 16) { ps[tid] = 0.f; pe[tid] = 0.f; pc[tid] = 0.f; }
    __syncthreads();

    // ---- A fragments (packed layout): chunk = (brow>>4)*4 + ks, slot = lane ----
    const u16* Abase = Fb + (size_t)((brow >> 4) * 4) * 512 + lane * 8;
    bf16x8 afr[4];
    #pragma unroll
    for (int ks = 0; ks < 4; ++ks) afr[ks] = *(const bf16x8*)(Abase + ks * 512);

    unsigned char labr_[4];
    #pragma unroll
    for (int e = 0; e < 4; ++e) labr_[e] = labc[brow + quad * 4 + e];

    // column labels for this wave's 16 sub-tiles -> registers (static index)
    unsigned char lcol[16];
    #pragma unroll
    for (int i = 0; i < 16; ++i) lcol[i] = labc[wave * 256 + i * 16 + l16];

    // register accumulators for positives (rows quad*4+e)
    float pps[4] = {0.f, 0.f, 0.f, 0.f};
    float ppe[4] = {0.f, 0.f, 0.f, 0.f};
    float ppc[4] = {0.f, 0.f, 0.f, 0.f};

    // ---- phase 1: sweep 8 n-tiles of 32 cols (packed lane-contiguous loads) ----
    const u16* Bwv = Fb + (size_t)(wave * 16) * 4 * 512 + lane * 8;  // wave's chunk base
    #pragma unroll
    for (int t = 0; t < 8; ++t) {
        floatx4 a0 = (floatx4){0.f, 0.f, 0.f, 0.f};
        floatx4 a1 = (floatx4){0.f, 0.f, 0.f, 0.f};
        #pragma unroll
        for (int ks = 0; ks < 4; ++ks) {
            bf16x8 b0 = *(const bf16x8*)(Bwv + (size_t)((t * 2)     * 4 + ks) * 512);
            bf16x8 b1 = *(const bf16x8*)(Bwv + (size_t)((t * 2 + 1) * 4 + ks) * 512);
            a0 = __builtin_amdgcn_mfma_f32_16x16x32_bf16(afr[ks], b0, a0, 0, 0, 0);
            a1 = __builtin_amdgcn_mfma_f32_16x16x32_bf16(afr[ks], b1, a1, 0, 0, 0);
        }
        // epilogue: C/D map col = l16 (B side), row = quad*4+e (A side) [m89/m91]
        const int tn0 = wave * 256 + t * 32;
        #pragma unroll
        for (int nt = 0; nt < 2; ++nt) {
            const floatx4 accv = nt ? a1 : a0;
            const int cg_ = tn0 + nt * 16 + l16;       // global col
            const int lc = lcol[t * 2 + nt];           // register, static index
            #pragma unroll
            for (int e = 0; e < 4; ++e) {
                const int rl = quad * 4 + e;
                const int rg = brow + rl;
                if (cg_ == rg) continue;               // diagonal
                const float s = accv[e];
                const bool pos = (lc == (int)labr_[e]);  // positive (~41/row total)
                if (pos | (s > TGUESS)) {
                    const float ex = __expf((s - 1.f) * 10.f);
                    if (pos) {                         // register accumulate
                        pps[e] += s; ppe[e] += ex; ppc[e] += 1.f;
                    } else {                           // hard negative -> histogram
                        int b = (int)((s - 0.1f) * 800.f);
                        b = b < 0 ? 0 : (b > HBINS - 1 ? HBINS - 1 : b);
                        atomicAdd(&hcnt[rl * HBINS + b], 1);     // fire-and-forget
                        atomicAdd(&hexp[rl * HBINS + b], ex);    // fire-and-forget
                    }
                }
            }
        }
    }

    // ---- fold positive partials: reduce over the 16-lane l16 group, 1 atomic/row/wave ----
    #pragma unroll
    for (int e = 0; e < 4; ++e) {
        float a = pps[e], b = ppe[e], c = ppc[e];
        #pragma unroll
        for (int off = 8; off; off >>= 1) {
            a += __shfl_xor(a, off);
            b += __shfl_xor(b, off);
            c += __shfl_xor(c, off);
        }
        if (l16 == 0) {
            const int rl = quad * 4 + e;
            atomicAdd(&ps[rl], a);
            atomicAdd(&pe[rl], b);
            atomicAdd(&pc[rl], c);
        }
    }
    __syncthreads();

    // ---- phase 2: wave r = threshold bin + loss for row r (wave-private) ----
    {
        const int r = wave;
        const int* hc = hcnt + r * HBINS;
        const float* hx = hexp + r * HBINS;

        int local[8], csum = 0;                        // lane owns bins [lane*8, lane*8+8)
        #pragma unroll
        for (int t2 = 0; t2 < 8; ++t2) { local[t2] = hc[lane * 8 + t2]; csum += local[t2]; }
        int suf = csum;
        #pragma unroll
        for (int off = 1; off < 64; off <<= 1) {       // wave suffix-sum
            int t2 = __shfl_down(suf, off);
            if (lane + off < 64) suf += t2;
        }
        const int above = suf - csum;
        const bool owner = (above < K_TOP) && (suf >= K_TOP);
        int b1o = 0, c1o = 0;
        if (owner) {
            int acc2 = above;
            #pragma unroll
            for (int t2 = 7; t2 >= 0; --t2) {
                if (acc2 + local[t2] >= K_TOP) { b1o = lane * 8 + t2; c1o = acc2; break; }
                acc2 += local[t2];
            }
        }
        unsigned long long bm = __ballot(owner);
        int b1, K2;
        if (bm == 0ull) {            // fewer than K_TOP candidates: take them all
            b1 = -1; K2 = 0;
        } else {
            const int src = __ffsll((long long)bm) - 1;
            b1 = __shfl(b1o, src);
            K2 = K_TOP - __shfl(c1o, src);
        }

        float te = 0.f;                                // exact exp-sum above bin b1
        #pragma unroll
        for (int t2 = 0; t2 < 8; ++t2) {
            const int b = lane * 8 + t2;
            if (b > b1) te += hx[b];
        }
        #pragma unroll
        for (int off = 32; off; off >>= 1) te += __shfl_down(te, off);

        if (lane == 0) {
            float tsum = 0.f;
            if (K2 > 0) {
                const int cb = hc[b1];
                if (cb > 0) tsum = (float)K2 * hx[b1] / (float)cb;  // in-bin average
            }
            const float pcnt = pc[r];
            const int labi = labc[brow + r];
            float pr = 0.f, vd = 0.f;
            if (labi > 0 && pcnt > 0.f) {
                float denom = pe[r] + te + tsum;
                float slp = 10.f * (ps[r] - pcnt) - pcnt * logf(denom);
                pr = -2.f * slp / pcnt;
                vd = 1.f;
            }
            rowout[brow + r] = make_float2(pr, vd);
        }
    }
}

// ---------------- tree-reduce 4096 row results -> scalar ----------------
__global__ __launch_bounds__(256) void reduce_kernel(const float2* __restrict__ rowout,
                                                     float* __restrict__ out) {
    __shared__ float reda[4], redb[4];
    const int tid = threadIdx.x, lane = tid & 63, w = tid >> 6;
    float sa = 0.f, sb = 0.f;
    #pragma unroll
    for (int j = 0; j < 16; ++j) {
        float2 v = rowout[j * 256 + tid];
        sa += v.x; sb += v.y;
    }
    #pragma unroll
    for (int off = 32; off; off >>= 1) {
        sa += __shfl_down(sa, off);
        sb += __shfl_down(sb, off);
    }
    if (lane == 0) { reda[w] = sa; redb[w] = sb; }
    __syncthreads();
    if (tid == 0)
        out[0] = (reda[0] + reda[1] + reda[2] + reda[3]) /
                 (redb[0] + redb[1] + redb[2] + redb[3]);
}

extern "C" void kernel_launch(void* const* d_in, const int* in_sizes, int n_in,
                              void* d_out, int out_size, void* d_ws, size_t ws_size,
                              hipStream_t stream) {
    const float* F      = (const float*)d_in[0];
    const int*   labels = (const int*)d_in[1];
    float*       out    = (float*)d_out;

    char* w = (char*)d_ws;
    u16*    Fb     = (u16*)w;               w += (size_t)BSZ * DIM * 2;   // 1 MB
    float2* rowout = (float2*)w;            w += (size_t)BSZ * 8;         // 32 KB

    pre_kernel<<<256, 256, 0, stream>>>(F, Fb);
    fused_all<<<256, 1024, 0, stream>>>(Fb, labels, rowout);
    reduce_kernel<<<1, 256, 0, stream>>>(rowout, out);
}